// Round 2
// baseline (4223.809 us; speedup 1.0000x reference)
//
#include <hip/hip_runtime.h>
#include <hip/hip_bf16.h>

// Swin block fp32 I/O: B=8, H=W=128, C=192, NH=6, hd=32, WS=8, SS=4.
// 2048 windows x 64 tokens.
//   k_attn: gathered x -> qkv (per-window GEMM) -> attention -> proj -> +x -> xres (f32 ws)
//   k_mlp:  LN + MLP(gelu exact) + residual -> out (f32)
// Round 2: fp32 I/O (reference dtype), VALU compute, bf16 LDS activations.

typedef __hip_bfloat16 bf16;

__device__ __forceinline__ float b2f(bf16 v) { return __bfloat162float(v); }
__device__ __forceinline__ bf16  f2b(float v) { return __float2bfloat16(v); }

// ---------------------------------------------------------------------------
// Kernel 1: fused qkv + window attention + proj + residual
// grid 2048 blocks x 256 threads
// ---------------------------------------------------------------------------
__global__ __launch_bounds__(256) void k_attn(
    const float* __restrict__ x, const float* __restrict__ qkv_w,
    const float* __restrict__ qkv_b, const float* __restrict__ proj_w,
    const float* __restrict__ proj_b, const float* __restrict__ rpb,
    float* __restrict__ xres)
{
    __shared__ __align__(16) bf16  sX[64 * 196];     // gathered window rows (bf16)
    __shared__ __align__(16) bf16  sQKV[64 * 580];   // qkv rows; O overwrites q region
    __shared__ __align__(16) float sW[192 * 64];     // streamed weight tile (fp32)
    __shared__ float sRPB[1360];

    const int t   = threadIdx.x;
    const int win = blockIdx.x;
    const int b   = win >> 8;
    const int wi  = win & 255;
    const int wh  = wi >> 4, ww = wi & 15;

    // stage gathered x window [64,192] -> bf16 LDS
    {
        int row = t >> 2;
        int cg  = (t & 3) * 48;
        int r = row >> 3, c = row & 7;
        int hs = (wh * 8 + r + 4) & 127;             // roll(-4)
        int wsX = (ww * 8 + c + 4) & 127;
        const float4* src = reinterpret_cast<const float4*>(
            x + (((size_t)b * 128 + hs) * 128 + wsX) * 192 + cg);
        #pragma unroll
        for (int u = 0; u < 12; u++) {
            float4 f = src[u];
            sX[row * 196 + cg + u * 4]     = f2b(f.x);
            sX[row * 196 + cg + u * 4 + 1] = f2b(f.y);
            sX[row * 196 + cg + u * 4 + 2] = f2b(f.z);
            sX[row * 196 + cg + u * 4 + 3] = f2b(f.w);
        }
    }
    for (int i = t; i < 1350; i += 256) sRPB[i] = rpb[i];

    const int tr = (t >> 4) * 4;
    const int tc = (t & 15) * 4;

    // qkv = xwin @ qkv_w + qkv_b : 9 column chunks of 64
    for (int cb = 0; cb < 9; cb++) {
        __syncthreads();
        for (int i = t; i < 192 * 16; i += 256) {
            int row = i >> 4, c4 = (i & 15) * 4;
            *reinterpret_cast<float4*>(&sW[row * 64 + c4]) =
                *reinterpret_cast<const float4*>(qkv_w + (size_t)row * 576 + cb * 64 + c4);
        }
        __syncthreads();
        float acc[4][4] = {};
        for (int k = 0; k < 192; k++) {
            float4 bv = *reinterpret_cast<const float4*>(&sW[k * 64 + tc]);
            float a[4];
            #pragma unroll
            for (int i = 0; i < 4; i++) a[i] = b2f(sX[(tr + i) * 196 + k]);
            #pragma unroll
            for (int i = 0; i < 4; i++) {
                acc[i][0] += a[i] * bv.x; acc[i][1] += a[i] * bv.y;
                acc[i][2] += a[i] * bv.z; acc[i][3] += a[i] * bv.w;
            }
        }
        #pragma unroll
        for (int i = 0; i < 4; i++)
            #pragma unroll
            for (int j = 0; j < 4; j++)
                sQKV[(tr + i) * 580 + cb * 64 + tc + j] =
                    f2b(acc[i][j] + qkv_b[cb * 64 + tc + j]);
    }
    __syncthreads();

    // attention: wave w handles heads w, w+4 (waves 2,3: one head)
    {
        const int wave = t >> 6, lane = t & 63;
        const int ri = lane >> 3, ci = lane & 7;
        const int gr = wh * 8 + ri, gc = ww * 8 + ci;
        const int regi = (gr < 120 ? 0 : (gr < 124 ? 1 : 2)) * 3
                       + (gc < 120 ? 0 : (gc < 124 ? 1 : 2));

        for (int h = wave; h < 6; h += 4) {
            float qreg[32];
            #pragma unroll
            for (int d = 0; d < 32; d += 2) {
                float2 f = __bfloat1622float2(*reinterpret_cast<const __hip_bfloat162*>(
                    &sQKV[lane * 580 + h * 32 + d]));
                qreg[d] = f.x; qreg[d + 1] = f.y;
            }
            float S[64];
            for (int j = 0; j < 64; j++) {
                const __hip_bfloat162* k2 = reinterpret_cast<const __hip_bfloat162*>(
                    &sQKV[j * 580 + 192 + h * 32]);
                float s = 0.f;
                #pragma unroll
                for (int d = 0; d < 16; d++) {
                    float2 f = __bfloat1622float2(k2[d]);
                    s += qreg[2 * d] * f.x + qreg[2 * d + 1] * f.y;
                }
                int rj = j >> 3, cj = j & 7;
                int grj = wh * 8 + rj, gcj = ww * 8 + cj;
                int regj = (grj < 120 ? 0 : (grj < 124 ? 1 : 2)) * 3
                         + (gcj < 120 ? 0 : (gcj < 124 ? 1 : 2));
                float bias = sRPB[((ri - rj + 7) * 15 + (ci - cj + 7)) * 6 + h];
                S[j] = s * 0.1767766952966369f + bias + (regi == regj ? 0.f : -100.f);
            }
            float m = S[0];
            #pragma unroll
            for (int j = 1; j < 64; j++) m = fmaxf(m, S[j]);
            float sum = 0.f;
            #pragma unroll
            for (int j = 0; j < 64; j++) { S[j] = __expf(S[j] - m); sum += S[j]; }
            float inv = 1.f / sum;
            // O overwrites q region (cols h*32..h*32+31); own-row q already in qreg,
            // and only this wave touches columns of head h.
            for (int dp = 0; dp < 16; dp++) {
                float a0 = 0.f, a1 = 0.f;
                #pragma unroll
                for (int j = 0; j < 64; j++) {
                    float2 f = __bfloat1622float2(*reinterpret_cast<const __hip_bfloat162*>(
                        &sQKV[j * 580 + 384 + h * 32 + dp * 2]));
                    a0 += S[j] * f.x; a1 += S[j] * f.y;
                }
                sQKV[lane * 580 + h * 32 + dp * 2]     = f2b(a0 * inv);
                sQKV[lane * 580 + h * 32 + dp * 2 + 1] = f2b(a1 * inv);
            }
        }
    }

    // proj + residual + reverse-shift scatter : 3 column chunks of 64
    for (int cb = 0; cb < 3; cb++) {
        __syncthreads();
        for (int i = t; i < 192 * 16; i += 256) {
            int row = i >> 4, c4 = (i & 15) * 4;
            *reinterpret_cast<float4*>(&sW[row * 64 + c4]) =
                *reinterpret_cast<const float4*>(proj_w + (size_t)row * 192 + cb * 64 + c4);
        }
        __syncthreads();
        float acc[4][4] = {};
        for (int k = 0; k < 192; k++) {
            float4 bv = *reinterpret_cast<const float4*>(&sW[k * 64 + tc]);
            float a[4];
            #pragma unroll
            for (int i = 0; i < 4; i++) a[i] = b2f(sQKV[(tr + i) * 580 + k]);
            #pragma unroll
            for (int i = 0; i < 4; i++) {
                acc[i][0] += a[i] * bv.x; acc[i][1] += a[i] * bv.y;
                acc[i][2] += a[i] * bv.z; acc[i][3] += a[i] * bv.w;
            }
        }
        #pragma unroll
        for (int i = 0; i < 4; i++) {
            int n = tr + i;
            int sr = wh * 8 + (n >> 3), sc = ww * 8 + (n & 7);
            int h2 = (sr + 4) & 127, w2 = (sc + 4) & 127;   // roll(+4)
            size_t tok = ((size_t)b * 16384) + h2 * 128 + w2;
            const float4 xr = *reinterpret_cast<const float4*>(
                x + tok * 192 + cb * 64 + tc);
            float4 o;
            o.x = acc[i][0] + proj_b[cb * 64 + tc]     + xr.x;
            o.y = acc[i][1] + proj_b[cb * 64 + tc + 1] + xr.y;
            o.z = acc[i][2] + proj_b[cb * 64 + tc + 2] + xr.z;
            o.w = acc[i][3] + proj_b[cb * 64 + tc + 3] + xr.w;
            *reinterpret_cast<float4*>(xres + tok * 192 + cb * 64 + tc) = o;
        }
    }
}

// ---------------------------------------------------------------------------
// Kernel 2: LayerNorm + MLP (exact GELU) + residual -> out (fp32)
// grid 2048 blocks x 256 threads; block = 64 tokens
// ---------------------------------------------------------------------------
__global__ __launch_bounds__(256) void k_mlp(
    const float* __restrict__ xres, const float* __restrict__ g,
    const float* __restrict__ bb, const float* __restrict__ w1,
    const float* __restrict__ b1, const float* __restrict__ w2,
    const float* __restrict__ b2, float* __restrict__ out)
{
    __shared__ __align__(16) bf16  xnS[64 * 200];
    __shared__ __align__(16) bf16  hS[64 * 200];
    __shared__ __align__(16) float wF[96 * 192];
    __shared__ float red[512];
    __shared__ float meanS[64], rstdS[64];

    const int t = threadIdx.x;
    const size_t row0 = (size_t)blockIdx.x * 64;
    const int n  = t >> 2;
    const int c0 = (t & 3) * 48;

    // LN stats + xn
    {
        float v[48];
        const float4* src = reinterpret_cast<const float4*>(
            xres + (row0 + n) * 192 + c0);
        float s = 0.f, sq = 0.f;
        #pragma unroll
        for (int u = 0; u < 12; u++) {
            float4 f = src[u];
            v[u * 4] = f.x; v[u * 4 + 1] = f.y; v[u * 4 + 2] = f.z; v[u * 4 + 3] = f.w;
            s  += f.x + f.y + f.z + f.w;
            sq += f.x * f.x + f.y * f.y + f.z * f.z + f.w * f.w;
        }
        red[t] = s; red[256 + t] = sq;
        __syncthreads();
        if (t < 64) {
            float ss = red[t * 4] + red[t * 4 + 1] + red[t * 4 + 2] + red[t * 4 + 3];
            float qq = red[256 + t * 4] + red[256 + t * 4 + 1]
                     + red[256 + t * 4 + 2] + red[256 + t * 4 + 3];
            float mean = ss * (1.f / 192.f);
            float var  = qq * (1.f / 192.f) - mean * mean;
            meanS[t] = mean;
            rstdS[t] = rsqrtf(var + 1e-5f);
        }
        __syncthreads();
        float mean = meanS[n], rstd = rstdS[n];
        #pragma unroll
        for (int j = 0; j < 48; j++) {
            float xn = (v[j] - mean) * rstd * g[c0 + j] + bb[c0 + j];
            xnS[n * 200 + c0 + j] = f2b(xn);
        }
    }

    float acc[48];
    #pragma unroll
    for (int j = 0; j < 48; j++) acc[j] = 0.f;

    for (int kc = 0; kc < 4; kc++) {
        float hacc[48];
        #pragma unroll
        for (int j = 0; j < 48; j++) hacc[j] = b1[kc * 192 + c0 + j];

        // MLP1 partial: h_chunk = xn @ W1[:, kc*192 : +192]
        for (int half = 0; half < 2; half++) {
            __syncthreads();
            for (int i = t; i < 96 * 48; i += 256) {
                int rr = i / 48, cc4 = (i % 48) * 4;
                *reinterpret_cast<float4*>(&wF[rr * 192 + cc4]) =
                    *reinterpret_cast<const float4*>(
                        w1 + (size_t)(half * 96 + rr) * 768 + kc * 192 + cc4);
            }
            __syncthreads();
            for (int k = 0; k < 96; k++) {
                float a = b2f(xnS[n * 200 + half * 96 + k]);
                const float4* wr = reinterpret_cast<const float4*>(&wF[k * 192 + c0]);
                #pragma unroll
                for (int j4 = 0; j4 < 12; j4++) {
                    float4 w = wr[j4];
                    hacc[j4 * 4]     += a * w.x; hacc[j4 * 4 + 1] += a * w.y;
                    hacc[j4 * 4 + 2] += a * w.z; hacc[j4 * 4 + 3] += a * w.w;
                }
            }
        }
        // exact GELU -> hS
        #pragma unroll
        for (int j = 0; j < 48; j++) {
            float hv = hacc[j];
            float ge = 0.5f * hv * (1.f + erff(hv * 0.70710678118654752f));
            hS[n * 200 + c0 + j] = f2b(ge);
        }
        // MLP2 accumulate: acc += h_chunk @ W2[kc*192 : +192, :]
        for (int half = 0; half < 2; half++) {
            __syncthreads();
            for (int i = t; i < 96 * 48; i += 256) {
                int rr = i / 48, cc4 = (i % 48) * 4;
                *reinterpret_cast<float4*>(&wF[rr * 192 + cc4]) =
                    *reinterpret_cast<const float4*>(
                        w2 + (size_t)(kc * 192 + half * 96 + rr) * 192 + cc4);
            }
            __syncthreads();
            for (int k = 0; k < 96; k++) {
                float a = b2f(hS[n * 200 + half * 96 + k]);
                const float4* wr = reinterpret_cast<const float4*>(&wF[k * 192 + c0]);
                #pragma unroll
                for (int j4 = 0; j4 < 12; j4++) {
                    float4 w = wr[j4];
                    acc[j4 * 4]     += a * w.x; acc[j4 * 4 + 1] += a * w.y;
                    acc[j4 * 4 + 2] += a * w.z; acc[j4 * 4 + 3] += a * w.w;
                }
            }
        }
    }
    // epilogue: out = xres + mlp + b2 (fp32)
    {
        const float* xr = xres + (row0 + n) * 192 + c0;
        float* orow = out + (row0 + n) * 192 + c0;
        #pragma unroll
        for (int j = 0; j < 48; j++)
            orow[j] = xr[j] + acc[j] + b2[c0 + j];
    }
}

// ---------------------------------------------------------------------------
extern "C" void kernel_launch(void* const* d_in, const int* in_sizes, int n_in,
                              void* d_out, int out_size, void* d_ws, size_t ws_size,
                              hipStream_t stream)
{
    (void)in_sizes; (void)n_in; (void)out_size; (void)ws_size;

    const float* x      = (const float*)d_in[0];
    const float* qkv_w  = (const float*)d_in[1];
    const float* qkv_b  = (const float*)d_in[2];
    const float* proj_w = (const float*)d_in[3];
    const float* proj_b = (const float*)d_in[4];
    const float* rpb    = (const float*)d_in[5];
    const float* n2g    = (const float*)d_in[6];
    const float* n2b    = (const float*)d_in[7];
    const float* w1     = (const float*)d_in[8];
    const float* b1     = (const float*)d_in[9];
    const float* w2     = (const float*)d_in[10];
    const float* b2     = (const float*)d_in[11];
    // d_in[12], d_in[13] = H, W (int, static = 128)

    float* xres = (float*)d_ws;            // 131072 * 192 * 4 = 100.7 MB
    float* out  = (float*)d_out;

    hipLaunchKernelGGL(k_attn, dim3(2048), dim3(256), 0, stream,
                       x, qkv_w, qkv_b, proj_w, proj_b, rpb, xres);
    hipLaunchKernelGGL(k_mlp,  dim3(2048), dim3(256), 0, stream,
                       xres, n2g, n2b, w1, b1, w2, b2, out);
}

// Round 3
// 587.480 us; speedup vs baseline: 7.1897x; 7.1897x over previous
//
#include <hip/hip_runtime.h>
#include <hip/hip_bf16.h>

// Swin block fp32 I/O, MFMA bf16 compute. B=8,H=W=128,C=192,NH=6,hd=32,WS=8,SS=4.
// k_prep: weights -> bf16 transposed/padded chunk-major images + bias/mask table (ws)
// k_attn: per-window fused qkv GEMM -> attention -> proj -> +x -> xres (f32)
// k_mlp : LN -> MLP1 -> GELU -> MLP2 -> +xres -> out (f32), 128-row tiles
//
// MFMA 16x16x32 bf16 layouts (HW-verified per guide):
//   A: a[j] = A[m=lane&15][k=quad*8+j]   (8 contiguous bf16 if A stored [m][k])
//   B: b[j] = B[k=quad*8+j][n=lane&15]   (8 contiguous bf16 if W^T stored [n][k])
//   D: d[reg] = D[row=quad*4+reg][col=lane&15]

typedef __hip_bfloat16 bf16;
typedef __attribute__((ext_vector_type(8))) short bfrag;
typedef __attribute__((ext_vector_type(4))) float ffrag;

__device__ __forceinline__ float b2f(bf16 v) { return __bfloat162float(v); }
__device__ __forceinline__ bf16  f2b(float v) { return __float2bfloat16(v); }

#define MFMA(a, b, c) __builtin_amdgcn_mfma_f32_16x16x32_bf16((a), (b), (c), 0, 0, 0)

// workspace element offsets (bytes)
#define WS_XRES   0ULL
#define WS_QKVT   100663296ULL                    // bf16 [6][96][200]
#define WS_PROJT  (WS_QKVT  + 230400ULL)          // bf16 [2][96][200]
#define WS_W1T    (WS_PROJT + 76800ULL)           // bf16 [6][128][200]
#define WS_W2T    (WS_W1T   + 307200ULL)          // bf16 [6][192][136]
#define WS_SB     (WS_W2T   + 313344ULL)          // f32  [4][6][64][64]

// async contiguous global->LDS copy, 256 threads, nbytes % 16 == 0
__device__ __forceinline__ void stage_lds(const void* g, void* l, int nbytes, int t) {
    const int lane16 = (t & 63) * 16;
    for (int base = (t >> 6) * 1024; base < nbytes; base += 4096) {
        int off = base + lane16;
        if (off < nbytes) {
            __builtin_amdgcn_global_load_lds(
                (const __attribute__((address_space(1))) void*)((const char*)g + off),
                (__attribute__((address_space(3))) void*)((char*)l + base),
                16, 0, 0);
        }
    }
}

__device__ __forceinline__ float gelu_t(float x) {
    // x * sigmoid(1.5957691216*(x + 0.044715 x^3)) == tanh-form GELU
    float y = x * (1.5957691216057308f + 0.07135481627f * x * x);
    return x * (1.f / (1.f + __expf(-y)));
}

// ---------------------------------------------------------------------------
// k_prep: build bf16 transposed weight images + bias/mask table
// grid 2196 x 256 (562176 elements exactly)
// ---------------------------------------------------------------------------
__global__ __launch_bounds__(256) void k_prep(
    const float* __restrict__ qkv_w, const float* __restrict__ proj_w,
    const float* __restrict__ w1, const float* __restrict__ w2,
    const float* __restrict__ rpb, char* __restrict__ ws)
{
    int i = blockIdx.x * 256 + threadIdx.x;
    bf16* qkvT  = (bf16*)(ws + WS_QKVT);
    bf16* projT = (bf16*)(ws + WS_PROJT);
    bf16* w1T   = (bf16*)(ws + WS_W1T);
    bf16* w2T   = (bf16*)(ws + WS_W2T);
    float* sb   = (float*)(ws + WS_SB);

    if (i < 115200) {                              // qkvT [6][96][200]
        int c = i / 19200, r = (i % 19200) / 200, k = i % 200;
        qkvT[i] = f2b(k < 192 ? qkv_w[k * 576 + c * 96 + r] : 0.f);
    } else if (i < 153600) {                       // projT [2][96][200]
        int j = i - 115200;
        int c = j / 19200, r = (j % 19200) / 200, k = j % 200;
        projT[j] = f2b(k < 192 ? proj_w[k * 192 + c * 96 + r] : 0.f);
    } else if (i < 307200) {                       // w1T [6][128][200]
        int j = i - 153600;
        int c = j / 25600, r = (j % 25600) / 200, k = j % 200;
        w1T[j] = f2b(k < 192 ? w1[k * 768 + c * 128 + r] : 0.f);
    } else if (i < 463872) {                       // w2T [6][192][136]
        int j = i - 307200;
        int c = j / 26112, r = (j % 26112) / 136, kk = j % 136;
        w2T[j] = f2b(kk < 128 ? w2[(c * 128 + kk) * 192 + r] : 0.f);
    } else if (i < 562176) {                       // sb [4][6][64][64]
        int j = i - 463872;
        int cls = j / 24576, h = (j % 24576) / 4096;
        int ii = (j % 4096) / 64, jj = j % 64;
        int ri = ii >> 3, ci = ii & 7, rj = jj >> 3, cj = jj & 7;
        float bias = rpb[(((ri - rj + 7) * 15) + (ci - cj + 7)) * 6 + h];
        int clsR = cls >> 1, clsC = cls & 1;
        int regi = (clsR ? (ri < 4 ? 1 : 2) : 0) * 3 + (clsC ? (ci < 4 ? 1 : 2) : 0);
        int regj = (clsR ? (rj < 4 ? 1 : 2) : 0) * 3 + (clsC ? (cj < 4 ? 1 : 2) : 0);
        sb[j] = bias + (regi == regj ? 0.f : -100.f);
    }
}

// ---------------------------------------------------------------------------
// k_attn: one window per block, 4 waves; wave w owns output rows [16w,16w+16)
// ---------------------------------------------------------------------------
__global__ __launch_bounds__(256, 1) void k_attn(
    const float* __restrict__ x, const float* __restrict__ qkv_b,
    const float* __restrict__ proj_b, const char* __restrict__ ws,
    float* __restrict__ xres)
{
    __shared__ __align__(16) unsigned char smem[154112];
    bf16*  sX  = (bf16*)(smem);            // [64][200]  (later reused as sO)
    bf16*  sQK = (bf16*)(smem + 25600);    // [64][392]  Q cols 0..191, K cols 192..383
    bf16*  sVT = (bf16*)(smem + 75776);    // [6][32][72] V^T per head
    bf16*  sW  = (bf16*)(smem + 103424);   // [96][200]  weight chunk
    bf16*  sP  = (bf16*)(smem + 141824);   // [4][16][72] per-wave P
    float* sBq = (float*)(smem + 151040);  // [576]
    float* sBp = (float*)(smem + 153344);  // [192]

    const bf16* qkvT  = (const bf16*)(ws + WS_QKVT);
    const bf16* projT = (const bf16*)(ws + WS_PROJT);
    const float* sb   = (const float*)(ws + WS_SB);

    const int t    = threadIdx.x;
    const int lane = t & 63, quad = lane >> 4, l15 = lane & 15;
    const int wave = t >> 6, r0 = wave * 16;
    const int win = blockIdx.x;
    const int b   = win >> 8;
    const int wi  = win & 255;
    const int wh  = wi >> 4, wwi = wi & 15;

    // ---- stage gathered x window -> bf16 sX ----
    {
        int row = t >> 2;
        int cg  = (t & 3) * 48;
        int r = row >> 3, c = row & 7;
        int hs  = (wh * 8 + r + 4) & 127;
        int wsX = (wwi * 8 + c + 4) & 127;
        const float4* src = (const float4*)(x + ((size_t)(b * 16384 + hs * 128 + wsX)) * 192 + cg);
        __hip_bfloat162* dst = (__hip_bfloat162*)&sX[row * 200 + cg];
        #pragma unroll
        for (int u = 0; u < 12; u++) {
            float4 f = src[u];
            dst[u * 2]     = __float22bfloat162_rn({f.x, f.y});
            dst[u * 2 + 1] = __float22bfloat162_rn({f.z, f.w});
        }
    }
    for (int i = t; i < 576; i += 256) sBq[i] = qkv_b[i];
    if (t < 192) sBp[t] = proj_b[t];
    __syncthreads();

    // A-frags of x window (persist across qkv chunks)
    bfrag aX[6];
    #pragma unroll
    for (int kb = 0; kb < 6; kb++)
        aX[kb] = *(const bfrag*)&sX[(r0 + l15) * 200 + kb * 32 + quad * 8];

    // ---- qkv GEMM: 6 chunks of 96 cols ----
    for (int cb = 0; cb < 6; cb++) {
        __syncthreads();
        stage_lds(qkvT + cb * 19200, sW, 38400, t);
        __syncthreads();
        #pragma unroll
        for (int ct = 0; ct < 6; ct++) {
            bfrag bw[6];
            #pragma unroll
            for (int kb = 0; kb < 6; kb++)
                bw[kb] = *(const bfrag*)&sW[(ct * 16 + l15) * 200 + kb * 32 + quad * 8];
            ffrag acc = {0.f, 0.f, 0.f, 0.f};
            #pragma unroll
            for (int kb = 0; kb < 6; kb++) acc = MFMA(aX[kb], bw[kb], acc);
            int col = cb * 96 + ct * 16 + l15;
            float bias = sBq[col];
            if (col < 384) {
                #pragma unroll
                for (int reg = 0; reg < 4; reg++)
                    sQK[(r0 + quad * 4 + reg) * 392 + col] = f2b(acc[reg] + bias);
            } else {
                int hh = (col - 384) >> 5, d = (col - 384) & 31;
                #pragma unroll
                for (int reg = 0; reg < 4; reg++)
                    sVT[(hh * 32 + d) * 72 + (r0 + quad * 4 + reg)] = f2b(acc[reg] + bias);
            }
        }
    }
    __syncthreads();   // qkv complete; sX free for reuse as sO

    // ---- attention ----
    bf16* sO  = sX;                         // [64][200]
    bf16* sPw = sP + wave * 16 * 72;
    const int cls = ((wh == 15) ? 2 : 0) + ((wwi == 15) ? 1 : 0);
    const float* bBc = sb + (size_t)cls * 6 * 4096;

    for (int h = 0; h < 6; h++) {
        bfrag aQ = *(const bfrag*)&sQK[(r0 + l15) * 392 + h * 32 + quad * 8];
        ffrag Sf[4];
        #pragma unroll
        for (int jt = 0; jt < 4; jt++) {
            bfrag bK = *(const bfrag*)&sQK[(jt * 16 + l15) * 392 + 192 + h * 32 + quad * 8];
            ffrag z = {0.f, 0.f, 0.f, 0.f};
            Sf[jt] = MFMA(aQ, bK, z);
        }
        const float* bB = bBc + h * 4096 + (r0 + quad * 4) * 64 + l15;
        #pragma unroll
        for (int jt = 0; jt < 4; jt++)
            #pragma unroll
            for (int reg = 0; reg < 4; reg++)
                Sf[jt][reg] = Sf[jt][reg] * 0.1767766952966369f + bB[reg * 64 + jt * 16];

        #pragma unroll
        for (int reg = 0; reg < 4; reg++) {
            float m = fmaxf(fmaxf(Sf[0][reg], Sf[1][reg]), fmaxf(Sf[2][reg], Sf[3][reg]));
            m = fmaxf(m, __shfl_xor(m, 1)); m = fmaxf(m, __shfl_xor(m, 2));
            m = fmaxf(m, __shfl_xor(m, 4)); m = fmaxf(m, __shfl_xor(m, 8));
            float s = 0.f;
            #pragma unroll
            for (int jt = 0; jt < 4; jt++) { Sf[jt][reg] = __expf(Sf[jt][reg] - m); s += Sf[jt][reg]; }
            s += __shfl_xor(s, 1); s += __shfl_xor(s, 2);
            s += __shfl_xor(s, 4); s += __shfl_xor(s, 8);
            float inv = 1.f / s;
            int prow = (quad * 4 + reg) * 72;
            #pragma unroll
            for (int jt = 0; jt < 4; jt++)
                sPw[prow + jt * 16 + l15] = f2b(Sf[jt][reg] * inv);
        }
        // P@V (within-wave LDS RAW; compiler inserts lgkmcnt)
        bfrag aP0 = *(const bfrag*)&sPw[l15 * 72 + quad * 8];
        bfrag aP1 = *(const bfrag*)&sPw[l15 * 72 + 32 + quad * 8];
        #pragma unroll
        for (int ct = 0; ct < 2; ct++) {
            bfrag bV0 = *(const bfrag*)&sVT[(h * 32 + ct * 16 + l15) * 72 + quad * 8];
            bfrag bV1 = *(const bfrag*)&sVT[(h * 32 + ct * 16 + l15) * 72 + 32 + quad * 8];
            ffrag z = {0.f, 0.f, 0.f, 0.f};
            ffrag o = MFMA(aP1, bV1, MFMA(aP0, bV0, z));
            #pragma unroll
            for (int reg = 0; reg < 4; reg++)
                sO[(r0 + quad * 4 + reg) * 200 + h * 32 + ct * 16 + l15] = f2b(o[reg]);
        }
    }

    // ---- proj + residual + reverse-shift scatter ----
    bfrag aO[6];
    #pragma unroll
    for (int kb = 0; kb < 6; kb++)
        aO[kb] = *(const bfrag*)&sO[(r0 + l15) * 200 + kb * 32 + quad * 8];

    size_t tokb[4];
    #pragma unroll
    for (int reg = 0; reg < 4; reg++) {
        int n = r0 + quad * 4 + reg;
        int sr = wh * 8 + (n >> 3), scc = wwi * 8 + (n & 7);
        int h2 = (sr + 4) & 127, w2c = (scc + 4) & 127;
        tokb[reg] = ((size_t)(b * 16384 + h2 * 128 + w2c)) * 192;
    }

    for (int cb = 0; cb < 2; cb++) {
        __syncthreads();
        stage_lds(projT + cb * 19200, sW, 38400, t);
        __syncthreads();
        #pragma unroll
        for (int ct = 0; ct < 6; ct++) {
            bfrag bw[6];
            #pragma unroll
            for (int kb = 0; kb < 6; kb++)
                bw[kb] = *(const bfrag*)&sW[(ct * 16 + l15) * 200 + kb * 32 + quad * 8];
            ffrag acc = {0.f, 0.f, 0.f, 0.f};
            #pragma unroll
            for (int kb = 0; kb < 6; kb++) acc = MFMA(aO[kb], bw[kb], acc);
            int col = cb * 96 + ct * 16 + l15;
            float pb = sBp[col];
            #pragma unroll
            for (int reg = 0; reg < 4; reg++) {
                float xr = x[tokb[reg] + col];
                xres[tokb[reg] + col] = acc[reg] + pb + xr;
            }
        }
    }
}

// ---------------------------------------------------------------------------
// k_mlp: 128 tokens per block, 4 waves; wave w owns rows [32w, 32w+32)
// ---------------------------------------------------------------------------
__global__ __launch_bounds__(256, 1) void k_mlp(
    const float* __restrict__ xres, const float* __restrict__ g,
    const float* __restrict__ bb, const float* __restrict__ b1,
    const float* __restrict__ b2, const char* __restrict__ ws,
    float* __restrict__ out)
{
    __shared__ __align__(16) unsigned char smem[145664];
    bf16*  xnS = (bf16*)(smem);            // [128][200]
    bf16*  wS  = (bf16*)(smem + 51200);    // max(51200, 52224)
    bf16*  hS  = (bf16*)(smem + 103424);   // [128][136]
    float* sB1 = (float*)(smem + 138240);  // [768]
    float* sB2 = (float*)(smem + 141312);  // [192]
    float* sG  = (float*)(smem + 142080);  // [192]
    float* sBt = (float*)(smem + 142848);  // [192]
    float* red = (float*)(smem + 143616);  // [512]

    const bf16* w1T = (const bf16*)(ws + WS_W1T);
    const bf16* w2T = (const bf16*)(ws + WS_W2T);

    const int t    = threadIdx.x;
    const int lane = t & 63, quad = lane >> 4, l15 = lane & 15;
    const int wave = t >> 6, r0 = wave * 32;
    const size_t row0 = (size_t)blockIdx.x * 128;

    for (int i = t; i < 768; i += 256) sB1[i] = b1[i];
    if (t < 192) { sB2[t] = b2[t]; sG[t] = g[t]; sBt[t] = bb[t]; }

    // ---- LayerNorm: 2 passes of 64 rows, 4 threads/row ----
    for (int p = 0; p < 2; p++) {
        int row = p * 64 + (t >> 2);
        int q   = t & 3;
        const float4* src = (const float4*)(xres + (row0 + row) * 192 + q * 48);
        float v[48];
        float s = 0.f, sq = 0.f;
        #pragma unroll
        for (int u = 0; u < 12; u++) {
            float4 f = src[u];
            v[u*4] = f.x; v[u*4+1] = f.y; v[u*4+2] = f.z; v[u*4+3] = f.w;
            s  += f.x + f.y + f.z + f.w;
            sq += f.x*f.x + f.y*f.y + f.z*f.z + f.w*f.w;
        }
        red[t] = s; red[256 + t] = sq;
        __syncthreads();
        int base = t & ~3;
        float ss = red[base] + red[base+1] + red[base+2] + red[base+3];
        float qq = red[256+base] + red[256+base+1] + red[256+base+2] + red[256+base+3];
        float mean = ss * (1.f / 192.f);
        float var  = qq * (1.f / 192.f) - mean * mean;
        float rstd = rsqrtf(var + 1e-5f);
        __hip_bfloat162* dst = (__hip_bfloat162*)&xnS[row * 200 + q * 48];
        #pragma unroll
        for (int u = 0; u < 24; u++) {
            float a0 = (v[u*2]   - mean) * rstd * sG[q*48 + u*2]   + sBt[q*48 + u*2];
            float a1 = (v[u*2+1] - mean) * rstd * sG[q*48 + u*2+1] + sBt[q*48 + u*2+1];
            dst[u] = __float22bfloat162_rn({a0, a1});
        }
        __syncthreads();
    }

    // A-frags of xn (persist)
    bfrag aX[2][6];
    #pragma unroll
    for (int rt = 0; rt < 2; rt++)
        #pragma unroll
        for (int kb = 0; kb < 6; kb++)
            aX[rt][kb] = *(const bfrag*)&xnS[(r0 + rt*16 + l15) * 200 + kb*32 + quad*8];

    ffrag oacc[2][12];
    #pragma unroll
    for (int rt = 0; rt < 2; rt++)
        #pragma unroll
        for (int ct = 0; ct < 12; ct++)
            oacc[rt][ct] = (ffrag){0.f, 0.f, 0.f, 0.f};

    for (int kc = 0; kc < 6; kc++) {
        __syncthreads();
        stage_lds(w1T + kc * 25600, wS, 51200, t);
        __syncthreads();
        // MLP1 + GELU -> hS
        #pragma unroll
        for (int ct = 0; ct < 8; ct++) {
            bfrag bw[6];
            #pragma unroll
            for (int kb = 0; kb < 6; kb++)
                bw[kb] = *(const bfrag*)&wS[(ct*16 + l15) * 200 + kb*32 + quad*8];
            float bias = sB1[kc * 128 + ct * 16 + l15];
            #pragma unroll
            for (int rt = 0; rt < 2; rt++) {
                ffrag a = {0.f, 0.f, 0.f, 0.f};
                #pragma unroll
                for (int kb = 0; kb < 6; kb++) a = MFMA(aX[rt][kb], bw[kb], a);
                #pragma unroll
                for (int reg = 0; reg < 4; reg++)
                    hS[(r0 + rt*16 + quad*4 + reg) * 136 + ct*16 + l15] =
                        f2b(gelu_t(a[reg] + bias));
            }
        }
        __syncthreads();
        stage_lds(w2T + kc * 26112, wS, 52224, t);
        __syncthreads();
        // MLP2 accumulate
        bfrag aH[2][4];
        #pragma unroll
        for (int rt = 0; rt < 2; rt++)
            #pragma unroll
            for (int k0 = 0; k0 < 4; k0++)
                aH[rt][k0] = *(const bfrag*)&hS[(r0 + rt*16 + l15) * 136 + k0*32 + quad*8];
        #pragma unroll
        for (int ct = 0; ct < 12; ct++) {
            bfrag bw[4];
            #pragma unroll
            for (int k0 = 0; k0 < 4; k0++)
                bw[k0] = *(const bfrag*)&wS[(ct*16 + l15) * 136 + k0*32 + quad*8];
            #pragma unroll
            for (int rt = 0; rt < 2; rt++)
                #pragma unroll
                for (int k0 = 0; k0 < 4; k0++)
                    oacc[rt][ct] = MFMA(aH[rt][k0], bw[k0], oacc[rt][ct]);
        }
    }

    // ---- epilogue: out = xres + mlp + b2 ----
    #pragma unroll
    for (int rt = 0; rt < 2; rt++)
        #pragma unroll
        for (int ct = 0; ct < 12; ct++) {
            int col = ct * 16 + l15;
            float b2v = sB2[col];
            #pragma unroll
            for (int reg = 0; reg < 4; reg++) {
                size_t gi = (row0 + r0 + rt*16 + quad*4 + reg) * 192 + col;
                out[gi] = xres[gi] + oacc[rt][ct][reg] + b2v;
            }
        }
}

// ---------------------------------------------------------------------------
extern "C" void kernel_launch(void* const* d_in, const int* in_sizes, int n_in,
                              void* d_out, int out_size, void* d_ws, size_t ws_size,
                              hipStream_t stream)
{
    (void)in_sizes; (void)n_in; (void)out_size; (void)ws_size;

    const float* x      = (const float*)d_in[0];
    const float* qkv_w  = (const float*)d_in[1];
    const float* qkv_b  = (const float*)d_in[2];
    const float* proj_w = (const float*)d_in[3];
    const float* proj_b = (const float*)d_in[4];
    const float* rpb    = (const float*)d_in[5];
    const float* n2g    = (const float*)d_in[6];
    const float* n2b    = (const float*)d_in[7];
    const float* w1     = (const float*)d_in[8];
    const float* b1     = (const float*)d_in[9];
    const float* w2     = (const float*)d_in[10];
    const float* b2     = (const float*)d_in[11];

    char*  ws   = (char*)d_ws;
    float* xres = (float*)(ws + WS_XRES);
    float* out  = (float*)d_out;

    hipLaunchKernelGGL(k_prep, dim3(2196), dim3(256), 0, stream,
                       qkv_w, proj_w, w1, w2, rpb, ws);
    hipLaunchKernelGGL(k_attn, dim3(2048), dim3(256), 0, stream,
                       x, qkv_b, proj_b, ws, xres);
    hipLaunchKernelGGL(k_mlp,  dim3(1024), dim3(256), 0, stream,
                       xres, n2g, n2b, b1, b2, ws, out);
}

// Round 4
// 566.876 us; speedup vs baseline: 7.4510x; 1.0363x over previous
//
#include <hip/hip_runtime.h>
#include <hip/hip_bf16.h>

// Swin block fp32 I/O, MFMA bf16 compute. B=8,H=W=128,C=192,NH=6,hd=32,WS=8,SS=4.
// Round 4: barrier-minimal, 2 blocks/CU.
//  k_prep: weight images (transposed, k-padded) + bf16 bias/mask table -> ws
//  k_attn: per-window qkv->attn(2 head-groups)->proj->+x -> xres ; 4 barriers
//  k_mlp : wave-local LN -> MLP1 -> GELU -> MLP2 -> +xres -> out ; 0 barriers
//
// MFMA 16x16x32 bf16 layouts (HW-verified):
//   A: a[j] = A[m=lane&15][k=quad*8+j]
//   B: b[j] = B[k=quad*8+j][n=lane&15]
//   D: d[reg] = D[row=quad*4+reg][col=lane&15]

typedef __hip_bfloat16 bf16;
typedef __attribute__((ext_vector_type(8))) short bfrag;
typedef __attribute__((ext_vector_type(4))) float ffrag;

__device__ __forceinline__ float b2f(bf16 v) { return __bfloat162float(v); }
__device__ __forceinline__ bf16  f2b(float v) { return __float2bfloat16(v); }

#define MFMA(a, b, c) __builtin_amdgcn_mfma_f32_16x16x32_bf16((a), (b), (c), 0, 0, 0)

// workspace byte offsets
#define WS_XRES  0ULL
#define WS_QKVT  100663296ULL                 // bf16 [576][200]
#define WS_PROJT (WS_QKVT  + 230400ULL)       // bf16 [192][200]
#define WS_W1T   (WS_PROJT + 76800ULL)        // bf16 [768][200]
#define WS_W2T   (WS_W1T   + 307200ULL)       // bf16 [12][192][72]
#define WS_SB    (WS_W2T   + 331776ULL)       // bf16 [4][6][64][64]

__device__ __forceinline__ float gelu_t(float x) {
    float y = x * (1.5957691216057308f + 0.07135481627f * x * x);
    return x * (1.f / (1.f + __expf(-y)));
}

// ---------------------------------------------------------------------------
// k_prep: 2232 x 256 = 571392 elements exactly
// ---------------------------------------------------------------------------
__global__ __launch_bounds__(256) void k_prep(
    const float* __restrict__ qkv_w, const float* __restrict__ proj_w,
    const float* __restrict__ w1, const float* __restrict__ w2,
    const float* __restrict__ rpb, char* __restrict__ ws)
{
    int i = blockIdx.x * 256 + threadIdx.x;
    bf16* qkvT  = (bf16*)(ws + WS_QKVT);
    bf16* projT = (bf16*)(ws + WS_PROJT);
    bf16* w1T   = (bf16*)(ws + WS_W1T);
    bf16* w2T   = (bf16*)(ws + WS_W2T);
    bf16* sbB   = (bf16*)(ws + WS_SB);

    if (i < 115200) {                              // qkvT [576][200]
        int c = i / 200, k = i % 200;
        qkvT[i] = f2b(k < 192 ? qkv_w[k * 576 + c] : 0.f);
    } else if (i < 153600) {                       // projT [192][200]
        int j = i - 115200;
        int c = j / 200, k = j % 200;
        projT[j] = f2b(k < 192 ? proj_w[k * 192 + c] : 0.f);
    } else if (i < 307200) {                       // w1T [768][200]
        int j = i - 153600;
        int c = j / 200, k = j % 200;
        w1T[j] = f2b(k < 192 ? w1[k * 768 + c] : 0.f);
    } else if (i < 473088) {                       // w2T [12][192][72]
        int j = i - 307200;
        int kc = j / 13824, r = (j % 13824) / 72, kk = j % 72;
        w2T[j] = f2b(kk < 64 ? w2[(kc * 64 + kk) * 192 + r] : 0.f);
    } else {                                       // sbB [4][6][64][64]
        int j = i - 473088;
        int cls = j / 24576, h = (j % 24576) / 4096;
        int ii = (j % 4096) / 64, jj = j % 64;
        int ri = ii >> 3, ci = ii & 7, rj = jj >> 3, cj = jj & 7;
        float bias = rpb[(((ri - rj + 7) * 15) + (ci - cj + 7)) * 6 + h];
        int clsR = cls >> 1, clsC = cls & 1;
        int regi = (clsR ? (ri < 4 ? 1 : 2) : 0) * 3 + (clsC ? (ci < 4 ? 1 : 2) : 0);
        int regj = (clsR ? (rj < 4 ? 1 : 2) : 0) * 3 + (clsC ? (cj < 4 ? 1 : 2) : 0);
        sbB[j] = f2b(bias + (regi == regj ? 0.f : -100.f));
    }
}

// ---------------------------------------------------------------------------
// k_attn: one window per block, 4 waves, wave owns rows [16w,16w+16)
// LDS 75264 B -> 2 blocks/CU. Heads in 2 groups of 3. 4 barriers.
// ---------------------------------------------------------------------------
__global__ __launch_bounds__(256, 2) void k_attn(
    const float* __restrict__ x, const float* __restrict__ qkv_b,
    const float* __restrict__ proj_b, const char* __restrict__ ws,
    float* __restrict__ xres)
{
    __shared__ __align__(16) unsigned char smem[75264];
    bf16* sXO = (bf16*)(smem);             // [64][200] x-window, then O
    bf16* sQ  = (bf16*)(smem + 25600);     // [64][104]  per head-group
    bf16* sK  = (bf16*)(smem + 38912);     // [64][104]
    bf16* sVT = (bf16*)(smem + 52224);     // [3][32][72]
    bf16* sP  = (bf16*)(smem + 66048);     // [4][16][72] per-wave P

    const bf16* qkvT  = (const bf16*)(ws + WS_QKVT);
    const bf16* projT = (const bf16*)(ws + WS_PROJT);
    const bf16* sbB   = (const bf16*)(ws + WS_SB);

    const int t    = threadIdx.x;
    const int lane = t & 63, quad = lane >> 4, l15 = lane & 15;
    const int wave = t >> 6, r0 = wave * 16;
    const int win = blockIdx.x;
    const int b   = win >> 8;
    const int wi  = win & 255;
    const int wh  = wi >> 4, wwi = wi & 15;

    // ---- stage gathered x window -> bf16 sXO ----
    {
        int row = t >> 2;
        int cg  = (t & 3) * 48;
        int r = row >> 3, c = row & 7;
        int hs  = (wh * 8 + r + 4) & 127;
        int wsX = (wwi * 8 + c + 4) & 127;
        const float4* src = (const float4*)(x + ((size_t)(b * 16384 + hs * 128 + wsX)) * 192 + cg);
        __hip_bfloat162* dst = (__hip_bfloat162*)&sXO[row * 200 + cg];
        #pragma unroll
        for (int u = 0; u < 12; u++) {
            float4 f = src[u];
            dst[u * 2]     = __float22bfloat162_rn({f.x, f.y});
            dst[u * 2 + 1] = __float22bfloat162_rn({f.z, f.w});
        }
    }
    __syncthreads();                                        // B1

    bfrag aX[6];
    #pragma unroll
    for (int kb = 0; kb < 6; kb++)
        aX[kb] = *(const bfrag*)&sXO[(r0 + l15) * 200 + kb * 32 + quad * 8];

    const int cls = ((wh == 15) ? 2 : 0) + ((wwi == 15) ? 1 : 0);
    const bf16* bBc = sbB + (size_t)cls * 24576;

    bf16* sPw = sP + wave * 16 * 72;

    for (int g = 0; g < 2; g++) {
        if (g) __syncthreads();                             // B3: protect QKV overwrite
        // ---- qkv for head group g: Q,K,V 96-col slabs ----
        #pragma unroll
        for (int part = 0; part < 3; part++) {
            #pragma unroll
            for (int ct = 0; ct < 6; ct++) {
                int col = part * 192 + g * 96 + ct * 16 + l15;
                bfrag bw[6];
                #pragma unroll
                for (int kb = 0; kb < 6; kb++)
                    bw[kb] = *(const bfrag*)&qkvT[col * 200 + kb * 32 + quad * 8];
                ffrag acc = {0.f, 0.f, 0.f, 0.f};
                #pragma unroll
                for (int kb = 0; kb < 6; kb++) acc = MFMA(aX[kb], bw[kb], acc);
                float bias = qkv_b[col];
                #pragma unroll
                for (int reg = 0; reg < 4; reg++) {
                    int r = r0 + quad * 4 + reg;
                    float v = acc[reg] + bias;
                    if (part == 0)      sQ[r * 104 + ct * 16 + l15] = f2b(v);
                    else if (part == 1) sK[r * 104 + ct * 16 + l15] = f2b(v);
                    else {
                        int c96 = ct * 16 + l15;
                        sVT[((c96 >> 5) * 32 + (c96 & 31)) * 72 + r] = f2b(v);
                    }
                }
            }
        }
        __syncthreads();                                    // B2/B4: qkv complete
        // ---- attention for heads 3g..3g+2 ----
        for (int hl = 0; hl < 3; hl++) {
            int h = g * 3 + hl;
            bfrag aQ = *(const bfrag*)&sQ[(r0 + l15) * 104 + hl * 32 + quad * 8];
            ffrag Sf[4];
            #pragma unroll
            for (int jt = 0; jt < 4; jt++) {
                bfrag bK = *(const bfrag*)&sK[(jt * 16 + l15) * 104 + hl * 32 + quad * 8];
                ffrag z = {0.f, 0.f, 0.f, 0.f};
                Sf[jt] = MFMA(aQ, bK, z);
            }
            const bf16* bb = bBc + h * 4096 + (r0 + quad * 4) * 64 + l15;
            #pragma unroll
            for (int jt = 0; jt < 4; jt++)
                #pragma unroll
                for (int reg = 0; reg < 4; reg++)
                    Sf[jt][reg] = Sf[jt][reg] * 0.1767766952966369f
                                + b2f(bb[reg * 64 + jt * 16]);
            #pragma unroll
            for (int reg = 0; reg < 4; reg++) {
                float m = fmaxf(fmaxf(Sf[0][reg], Sf[1][reg]), fmaxf(Sf[2][reg], Sf[3][reg]));
                m = fmaxf(m, __shfl_xor(m, 1)); m = fmaxf(m, __shfl_xor(m, 2));
                m = fmaxf(m, __shfl_xor(m, 4)); m = fmaxf(m, __shfl_xor(m, 8));
                float s = 0.f;
                #pragma unroll
                for (int jt = 0; jt < 4; jt++) { Sf[jt][reg] = __expf(Sf[jt][reg] - m); s += Sf[jt][reg]; }
                s += __shfl_xor(s, 1); s += __shfl_xor(s, 2);
                s += __shfl_xor(s, 4); s += __shfl_xor(s, 8);
                float inv = 1.f / s;
                int prow = (quad * 4 + reg) * 72;
                #pragma unroll
                for (int jt = 0; jt < 4; jt++)
                    sPw[prow + jt * 16 + l15] = f2b(Sf[jt][reg] * inv);
            }
            bfrag aP0 = *(const bfrag*)&sPw[l15 * 72 + quad * 8];
            bfrag aP1 = *(const bfrag*)&sPw[l15 * 72 + 32 + quad * 8];
            #pragma unroll
            for (int ct = 0; ct < 2; ct++) {
                bfrag bV0 = *(const bfrag*)&sVT[(hl * 32 + ct * 16 + l15) * 72 + quad * 8];
                bfrag bV1 = *(const bfrag*)&sVT[(hl * 32 + ct * 16 + l15) * 72 + 32 + quad * 8];
                ffrag z = {0.f, 0.f, 0.f, 0.f};
                ffrag o = MFMA(aP1, bV1, MFMA(aP0, bV0, z));
                #pragma unroll
                for (int reg = 0; reg < 4; reg++)
                    sXO[(r0 + quad * 4 + reg) * 200 + h * 32 + ct * 16 + l15] = f2b(o[reg]);
            }
        }
    }

    // ---- proj + residual + reverse-shift scatter (own rows; no barrier) ----
    bfrag aO[6];
    #pragma unroll
    for (int kb = 0; kb < 6; kb++)
        aO[kb] = *(const bfrag*)&sXO[(r0 + l15) * 200 + kb * 32 + quad * 8];

    size_t tokb[4];
    #pragma unroll
    for (int reg = 0; reg < 4; reg++) {
        int n = r0 + quad * 4 + reg;
        int sr = wh * 8 + (n >> 3), scc = wwi * 8 + (n & 7);
        int h2 = (sr + 4) & 127, w2c = (scc + 4) & 127;
        tokb[reg] = ((size_t)(b * 16384 + h2 * 128 + w2c)) * 192;
    }

    #pragma unroll
    for (int ct = 0; ct < 12; ct++) {
        int col = ct * 16 + l15;
        bfrag bw[6];
        #pragma unroll
        for (int kb = 0; kb < 6; kb++)
            bw[kb] = *(const bfrag*)&projT[col * 200 + kb * 32 + quad * 8];
        ffrag acc = {0.f, 0.f, 0.f, 0.f};
        #pragma unroll
        for (int kb = 0; kb < 6; kb++) acc = MFMA(aO[kb], bw[kb], acc);
        float pb = proj_b[col];
        #pragma unroll
        for (int reg = 0; reg < 4; reg++)
            xres[tokb[reg] + col] = acc[reg] + pb + x[tokb[reg] + col];
    }
}

// ---------------------------------------------------------------------------
// k_mlp: 128 tokens/block, wave owns rows [32w,32w+32). ZERO barriers.
// LDS 69632 B -> 2 blocks/CU.
// ---------------------------------------------------------------------------
__global__ __launch_bounds__(256, 2) void k_mlp(
    const float* __restrict__ xres, const float* __restrict__ g,
    const float* __restrict__ bb, const float* __restrict__ b1,
    const float* __restrict__ b2, const char* __restrict__ ws,
    float* __restrict__ out)
{
    __shared__ __align__(16) unsigned char smem[69632];
    bf16* xnS = (bf16*)(smem);             // [128][200]
    bf16* hS  = (bf16*)(smem + 51200);     // [128][72]

    const bf16* w1T = (const bf16*)(ws + WS_W1T);
    const bf16* w2T = (const bf16*)(ws + WS_W2T);

    const int t    = threadIdx.x;
    const int lane = t & 63, quad = lane >> 4, l15 = lane & 15;
    const int wave = t >> 6, r0 = wave * 32;
    const size_t row0 = (size_t)blockIdx.x * 128;

    // ---- wave-local LayerNorm: 2 sub-passes of 16 rows, 4 lanes/row ----
    #pragma unroll
    for (int p = 0; p < 2; p++) {
        int row = r0 + p * 16 + l15;
        const float4* src = (const float4*)(xres + (row0 + row) * 192 + quad * 48);
        float v[48];
        float s = 0.f, sq = 0.f;
        #pragma unroll
        for (int u = 0; u < 12; u++) {
            float4 f = src[u];
            v[u*4] = f.x; v[u*4+1] = f.y; v[u*4+2] = f.z; v[u*4+3] = f.w;
            s  += f.x + f.y + f.z + f.w;
            sq += f.x*f.x + f.y*f.y + f.z*f.z + f.w*f.w;
        }
        s  += __shfl_xor(s, 16);  s  += __shfl_xor(s, 32);
        sq += __shfl_xor(sq, 16); sq += __shfl_xor(sq, 32);
        float mean = s * (1.f / 192.f);
        float var  = sq * (1.f / 192.f) - mean * mean;
        float rstd = rsqrtf(var + 1e-5f);
        __hip_bfloat162* dst = (__hip_bfloat162*)&xnS[row * 200 + quad * 48];
        #pragma unroll
        for (int u = 0; u < 24; u++) {
            int c = quad * 48 + u * 2;
            float a0 = (v[u*2]   - mean) * rstd * g[c]     + bb[c];
            float a1 = (v[u*2+1] - mean) * rstd * g[c + 1] + bb[c + 1];
            dst[u] = __float22bfloat162_rn({a0, a1});
        }
    }

    // A-frags of xn (within-wave LDS RAW; compiler inserts lgkmcnt)
    bfrag aX[2][6];
    #pragma unroll
    for (int rt = 0; rt < 2; rt++)
        #pragma unroll
        for (int kb = 0; kb < 6; kb++)
            aX[rt][kb] = *(const bfrag*)&xnS[(r0 + rt*16 + l15) * 200 + kb*32 + quad*8];

    ffrag oacc[2][12];
    #pragma unroll
    for (int rt = 0; rt < 2; rt++)
        #pragma unroll
        for (int ct = 0; ct < 12; ct++)
            oacc[rt][ct] = (ffrag){0.f, 0.f, 0.f, 0.f};

    for (int kc = 0; kc < 12; kc++) {
        // MLP1 cols [kc*64, kc*64+64) + GELU -> hS (own rows)
        #pragma unroll
        for (int ct = 0; ct < 4; ct++) {
            int col = kc * 64 + ct * 16 + l15;
            bfrag bw[6];
            #pragma unroll
            for (int kb = 0; kb < 6; kb++)
                bw[kb] = *(const bfrag*)&w1T[col * 200 + kb * 32 + quad * 8];
            float bias = b1[col];
            #pragma unroll
            for (int rt = 0; rt < 2; rt++) {
                ffrag a = {0.f, 0.f, 0.f, 0.f};
                #pragma unroll
                for (int kb = 0; kb < 6; kb++) a = MFMA(aX[rt][kb], bw[kb], a);
                #pragma unroll
                for (int reg = 0; reg < 4; reg++)
                    hS[(r0 + rt*16 + quad*4 + reg) * 72 + ct*16 + l15] =
                        f2b(gelu_t(a[reg] + bias));
            }
        }
        // MLP2 over this 64-k chunk (own rows; within-wave RAW)
        bfrag aH[2][2];
        #pragma unroll
        for (int rt = 0; rt < 2; rt++)
            #pragma unroll
            for (int k0 = 0; k0 < 2; k0++)
                aH[rt][k0] = *(const bfrag*)&hS[(r0 + rt*16 + l15) * 72 + k0*32 + quad*8];
        #pragma unroll
        for (int ct = 0; ct < 12; ct++) {
            bfrag bw2[2];
            #pragma unroll
            for (int k0 = 0; k0 < 2; k0++)
                bw2[k0] = *(const bfrag*)&w2T[(kc*192 + ct*16 + l15) * 72 + k0*32 + quad*8];
            #pragma unroll
            for (int rt = 0; rt < 2; rt++)
                #pragma unroll
                for (int k0 = 0; k0 < 2; k0++)
                    oacc[rt][ct] = MFMA(aH[rt][k0], bw2[k0], oacc[rt][ct]);
        }
    }

    // ---- epilogue: out = xres + mlp + b2 ----
    #pragma unroll
    for (int rt = 0; rt < 2; rt++)
        #pragma unroll
        for (int ct = 0; ct < 12; ct++) {
            int col = ct * 16 + l15;
            float b2v = b2[col];
            #pragma unroll
            for (int reg = 0; reg < 4; reg++) {
                size_t gi = (row0 + r0 + rt*16 + quad*4 + reg) * 192 + col;
                out[gi] = xres[gi] + oacc[rt][ct][reg] + b2v;
            }
        }
}

// ---------------------------------------------------------------------------
extern "C" void kernel_launch(void* const* d_in, const int* in_sizes, int n_in,
                              void* d_out, int out_size, void* d_ws, size_t ws_size,
                              hipStream_t stream)
{
    (void)in_sizes; (void)n_in; (void)out_size; (void)ws_size;

    const float* x      = (const float*)d_in[0];
    const float* qkv_w  = (const float*)d_in[1];
    const float* qkv_b  = (const float*)d_in[2];
    const float* proj_w = (const float*)d_in[3];
    const float* proj_b = (const float*)d_in[4];
    const float* rpb    = (const float*)d_in[5];
    const float* n2g    = (const float*)d_in[6];
    const float* n2b    = (const float*)d_in[7];
    const float* w1     = (const float*)d_in[8];
    const float* b1     = (const float*)d_in[9];
    const float* w2     = (const float*)d_in[10];
    const float* b2     = (const float*)d_in[11];

    char*  ws   = (char*)d_ws;
    float* xres = (float*)(ws + WS_XRES);
    float* out  = (float*)d_out;

    hipLaunchKernelGGL(k_prep, dim3(2232), dim3(256), 0, stream,
                       qkv_w, proj_w, w1, w2, rpb, ws);
    hipLaunchKernelGGL(k_attn, dim3(2048), dim3(256), 0, stream,
                       x, qkv_b, proj_b, ws, xres);
    hipLaunchKernelGGL(k_mlp,  dim3(1024), dim3(256), 0, stream,
                       xres, n2g, n2b, b1, b2, ws, out);
}

// Round 5
// 469.797 us; speedup vs baseline: 8.9907x; 1.2066x over previous
//
#include <hip/hip_runtime.h>
#include <hip/hip_bf16.h>

// Swin block fp32 I/O, MFMA bf16 compute. B=8,H=W=128,C=192,NH=6,hd=32,WS=8,SS=4.
// Round 5: LDS-staged B operands (global_load_lds), kill 4x cross-wave L2 redundancy.
//  k_prep: weight images (group-contiguous qkv, transposed, k-padded) + bias/mask
//  k_attn: per-window qkv(LDS-staged W) -> attention -> O to global scratch
//  k_proj: O @ projW + x -> xres   (projT staged once per block)
//  k_mlp : LN -> MLP1 -> GELU -> MLP2 -> +xres -> out (w1/w2 chunks staged per kc)
//
// MFMA 16x16x32 bf16 layouts (HW-verified):
//   A: a[j] = A[m=lane&15][k=quad*8+j]
//   B: b[j] = B[k=quad*8+j][n=lane&15]
//   D: d[reg] = D[row=quad*4+reg][col=lane&15]

typedef __hip_bfloat16 bf16;
typedef __attribute__((ext_vector_type(8))) short bfrag;
typedef __attribute__((ext_vector_type(4))) float ffrag;

union bfu { bf16 h[8]; bfrag v; };

__device__ __forceinline__ float b2f(bf16 v) { return __bfloat162float(v); }
__device__ __forceinline__ bf16  f2b(float v) { return __float2bfloat16(v); }

#define MFMA(a, b, c) __builtin_amdgcn_mfma_f32_16x16x32_bf16((a), (b), (c), 0, 0, 0)

// workspace byte offsets
#define WS_XRES  0ULL
#define WS_OG    100663296ULL                  // bf16 [131072][192] attention output
#define WS_QKVTG 150994944ULL                  // bf16 [2][320][200] group-contiguous qkv_w^T
#define WS_QBG   151250944ULL                  // f32  [2][320] group-contiguous qkv_b
#define WS_PROJT 151253504ULL                  // bf16 [192][200]
#define WS_W1T   151330304ULL                  // bf16 [768][200]
#define WS_W2T   151637504ULL                  // bf16 [12][192][72]
#define WS_SB    151969280ULL                  // bf16 [4][6][64][64]

// async contiguous global->LDS copy; nbytes multiple of 1024; 256 threads
__device__ __forceinline__ void stage_lds(const void* g, void* l, int nbytes, int t) {
    const int lane16 = (t & 63) * 16;
    for (int base = (t >> 6) * 1024; base < nbytes; base += 4096) {
        if (base + lane16 < nbytes) {
            __builtin_amdgcn_global_load_lds(
                (const __attribute__((address_space(1))) void*)((const char*)g + base + lane16),
                (__attribute__((address_space(3))) void*)((char*)l + base),
                16, 0, 0);
        }
    }
}

__device__ __forceinline__ float gelu_t(float x) {
    float y = x * (1.5957691216057308f + 0.07135481627f * x * x);
    return x * (1.f / (1.f + __expf(-y)));
}

// ---------------------------------------------------------------------------
// k_prep: 2285 x 256 covers 584832 elements
// ---------------------------------------------------------------------------
__global__ __launch_bounds__(256) void k_prep(
    const float* __restrict__ qkv_w, const float* __restrict__ qkv_b,
    const float* __restrict__ proj_w, const float* __restrict__ w1,
    const float* __restrict__ w2, const float* __restrict__ rpb,
    char* __restrict__ ws)
{
    int i = blockIdx.x * 256 + threadIdx.x;
    bf16*  qkvTg = (bf16*)(ws + WS_QKVTG);
    float* qbg   = (float*)(ws + WS_QBG);
    bf16*  projT = (bf16*)(ws + WS_PROJT);
    bf16*  w1T   = (bf16*)(ws + WS_W1T);
    bf16*  w2T   = (bf16*)(ws + WS_W2T);
    bf16*  sbB   = (bf16*)(ws + WS_SB);

    if (i < 128000) {                          // qkvTg [2][320][200]
        int g = i / 64000, rem = i % 64000;
        int c = rem / 200, k = rem % 200;
        float v = 0.f;
        if (k < 192) {
            if (c < 96)       v = qkv_w[k * 576 + g * 96 + c];
            else if (c < 192) v = qkv_w[k * 576 + 192 + g * 96 + (c - 96)];
            else if (c < 288) v = qkv_w[k * 576 + 384 + g * 96 + (c - 192)];
        }
        qkvTg[i] = f2b(v);
    } else if (i < 128640) {                   // qbg [2][320]
        int j = i - 128000;
        int g = j / 320, c = j % 320;
        float v = 0.f;
        if (c < 96)       v = qkv_b[g * 96 + c];
        else if (c < 192) v = qkv_b[192 + g * 96 + (c - 96)];
        else if (c < 288) v = qkv_b[384 + g * 96 + (c - 192)];
        qbg[j] = v;
    } else if (i < 167040) {                   // projT [192][200]
        int j = i - 128640;
        int c = j / 200, k = j % 200;
        projT[j] = f2b(k < 192 ? proj_w[k * 192 + c] : 0.f);
    } else if (i < 320640) {                   // w1T [768][200]
        int j = i - 167040;
        int c = j / 200, k = j % 200;
        w1T[j] = f2b(k < 192 ? w1[k * 768 + c] : 0.f);
    } else if (i < 486528) {                   // w2T [12][192][72]
        int j = i - 320640;
        int kc = j / 13824, r = (j % 13824) / 72, kk = j % 72;
        w2T[j] = f2b(kk < 64 ? w2[(kc * 64 + kk) * 192 + r] : 0.f);
    } else if (i < 584832) {                   // sbB [4][6][64][64]
        int j = i - 486528;
        int cls = j / 24576, h = (j % 24576) / 4096;
        int ii = (j % 4096) / 64, jj = j % 64;
        int ri = ii >> 3, ci = ii & 7, rj = jj >> 3, cj = jj & 7;
        float bias = rpb[(((ri - rj + 7) * 15) + (ci - cj + 7)) * 6 + h];
        int clsR = cls >> 1, clsC = cls & 1;
        int regi = (clsR ? (ri < 4 ? 1 : 2) : 0) * 3 + (clsC ? (ci < 4 ? 1 : 2) : 0);
        int regj = (clsR ? (rj < 4 ? 1 : 2) : 0) * 3 + (clsC ? (cj < 4 ? 1 : 2) : 0);
        sbB[j] = f2b(bias + (regi == regj ? 0.f : -100.f));
    }
}

// ---------------------------------------------------------------------------
// k_attn: one window/block, 4 waves x 16 rows. qkv weights LDS-staged.
// O -> global scratch. LDS 75264 -> 2 blocks/CU.
// ---------------------------------------------------------------------------
__global__ __launch_bounds__(256, 2) void k_attn(
    const float* __restrict__ x, const char* __restrict__ ws,
    bf16* __restrict__ Og)
{
    __shared__ __align__(16) unsigned char smem[75264];
    bf16* sW  = (bf16*)(smem);             // [64 cols][200] staged weight chunk
    bf16* sQ  = (bf16*)(smem + 25600);     // [64][104]
    bf16* sK  = (bf16*)(smem + 38912);     // [64][104]
    bf16* sVT = (bf16*)(smem + 52224);     // [96][72]
    bf16* sP  = (bf16*)(smem + 66048);     // [4][16][72]

    const bf16*  qkvTg = (const bf16*)(ws + WS_QKVTG);
    const float* qbg   = (const float*)(ws + WS_QBG);
    const bf16*  sbB   = (const bf16*)(ws + WS_SB);

    const int t    = threadIdx.x;
    const int lane = t & 63, quad = lane >> 4, l15 = lane & 15;
    const int wave = t >> 6, r0 = wave * 16;
    const int win = blockIdx.x;
    const int b   = win >> 8;
    const int wi  = win & 255;
    const int wh  = wi >> 4, wwi = wi & 15;

    // A-frags of gathered x window, direct from global (fp32 -> bf16)
    bfrag aX[6];
    {
        int row = r0 + l15;
        int rr = row >> 3, cc = row & 7;
        int hs  = (wh * 8 + rr + 4) & 127;
        int wsx = (wwi * 8 + cc + 4) & 127;
        const float* xrow = x + ((size_t)(b * 16384 + hs * 128 + wsx)) * 192;
        #pragma unroll
        for (int kb = 0; kb < 6; kb++) {
            float4 f0 = *(const float4*)(xrow + kb * 32 + quad * 8);
            float4 f1 = *(const float4*)(xrow + kb * 32 + quad * 8 + 4);
            bfu u;
            u.h[0] = f2b(f0.x); u.h[1] = f2b(f0.y); u.h[2] = f2b(f0.z); u.h[3] = f2b(f0.w);
            u.h[4] = f2b(f1.x); u.h[5] = f2b(f1.y); u.h[6] = f2b(f1.z); u.h[7] = f2b(f1.w);
            aX[kb] = u.v;
        }
    }

    const int cls = ((wh == 15) ? 2 : 0) + ((wwi == 15) ? 1 : 0);
    const bf16* bBc = sbB + (size_t)cls * 24576;
    bf16* sPw = sP + wave * 16 * 72;

    for (int g = 0; g < 2; g++) {
        // ---- qkv for head group g: 5 staged chunks of 64 cols (288 used) ----
        for (int ch = 0; ch < 5; ch++) {
            __syncthreads();
            stage_lds(qkvTg + (size_t)(g * 320 + ch * 64) * 200, sW, 25600, t);
            __syncthreads();
            #pragma unroll
            for (int ct = 0; ct < 4; ct++) {
                int c0 = ch * 64 + ct * 16;
                if (c0 < 288) {
                    bfrag bw[6];
                    #pragma unroll
                    for (int kb = 0; kb < 6; kb++)
                        bw[kb] = *(const bfrag*)&sW[(ct * 16 + l15) * 200 + kb * 32 + quad * 8];
                    ffrag acc = {0.f, 0.f, 0.f, 0.f};
                    #pragma unroll
                    for (int kb = 0; kb < 6; kb++) acc = MFMA(aX[kb], bw[kb], acc);
                    float bias = qbg[g * 320 + c0 + l15];
                    #pragma unroll
                    for (int reg = 0; reg < 4; reg++) {
                        int r = r0 + quad * 4 + reg;
                        float v = acc[reg] + bias;
                        if (c0 < 96)       sQ[r * 104 + c0 + l15] = f2b(v);
                        else if (c0 < 192) sK[r * 104 + (c0 - 96) + l15] = f2b(v);
                        else               sVT[(c0 - 192 + l15) * 72 + r] = f2b(v);
                    }
                }
            }
        }
        __syncthreads();
        // ---- attention heads g*3 .. g*3+2 ----
        for (int hl = 0; hl < 3; hl++) {
            int h = g * 3 + hl;
            bfrag aQ = *(const bfrag*)&sQ[(r0 + l15) * 104 + hl * 32 + quad * 8];
            ffrag Sf[4];
            #pragma unroll
            for (int jt = 0; jt < 4; jt++) {
                bfrag bK = *(const bfrag*)&sK[(jt * 16 + l15) * 104 + hl * 32 + quad * 8];
                ffrag z = {0.f, 0.f, 0.f, 0.f};
                Sf[jt] = MFMA(aQ, bK, z);
            }
            const bf16* bb = bBc + h * 4096 + (r0 + quad * 4) * 64 + l15;
            #pragma unroll
            for (int jt = 0; jt < 4; jt++)
                #pragma unroll
                for (int reg = 0; reg < 4; reg++)
                    Sf[jt][reg] = Sf[jt][reg] * 0.1767766952966369f
                                + b2f(bb[reg * 64 + jt * 16]);
            #pragma unroll
            for (int reg = 0; reg < 4; reg++) {
                float m = fmaxf(fmaxf(Sf[0][reg], Sf[1][reg]), fmaxf(Sf[2][reg], Sf[3][reg]));
                m = fmaxf(m, __shfl_xor(m, 1)); m = fmaxf(m, __shfl_xor(m, 2));
                m = fmaxf(m, __shfl_xor(m, 4)); m = fmaxf(m, __shfl_xor(m, 8));
                float s = 0.f;
                #pragma unroll
                for (int jt = 0; jt < 4; jt++) { Sf[jt][reg] = __expf(Sf[jt][reg] - m); s += Sf[jt][reg]; }
                s += __shfl_xor(s, 1); s += __shfl_xor(s, 2);
                s += __shfl_xor(s, 4); s += __shfl_xor(s, 8);
                float inv = 1.f / s;
                int prow = (quad * 4 + reg) * 72;
                #pragma unroll
                for (int jt = 0; jt < 4; jt++)
                    sPw[prow + jt * 16 + l15] = f2b(Sf[jt][reg] * inv);
            }
            bfrag aP0 = *(const bfrag*)&sPw[l15 * 72 + quad * 8];
            bfrag aP1 = *(const bfrag*)&sPw[l15 * 72 + 32 + quad * 8];
            #pragma unroll
            for (int ct = 0; ct < 2; ct++) {
                bfrag bV0 = *(const bfrag*)&sVT[(hl * 32 + ct * 16 + l15) * 72 + quad * 8];
                bfrag bV1 = *(const bfrag*)&sVT[(hl * 32 + ct * 16 + l15) * 72 + 32 + quad * 8];
                ffrag z = {0.f, 0.f, 0.f, 0.f};
                ffrag o = MFMA(aP1, bV1, MFMA(aP0, bV0, z));
                #pragma unroll
                for (int reg = 0; reg < 4; reg++)
                    Og[((size_t)win * 64 + r0 + quad * 4 + reg) * 192 + h * 32 + ct * 16 + l15]
                        = f2b(o[reg]);
            }
        }
    }
}

// ---------------------------------------------------------------------------
// k_proj: 128 rows (2 windows)/block, 4 waves x 32 rows (rt=2).
// projT staged ONCE (76800 B), 1 barrier. -> xres (reverse-shift + residual)
// ---------------------------------------------------------------------------
__global__ __launch_bounds__(256, 2) void k_proj(
    const float* __restrict__ x, const float* __restrict__ proj_b,
    const char* __restrict__ ws, float* __restrict__ xres)
{
    __shared__ __align__(16) bf16 sWp[192 * 200];   // 76800 B

    const bf16* projT = (const bf16*)(ws + WS_PROJT);
    const bf16* Og    = (const bf16*)(ws + WS_OG);

    const int t    = threadIdx.x;
    const int lane = t & 63, quad = lane >> 4, l15 = lane & 15;
    const int wave = t >> 6, r0 = wave * 32;
    const size_t row0 = (size_t)blockIdx.x * 128;

    stage_lds(projT, sWp, 76800, t);

    // A-frags of O (global, bf16, contiguous 16B)
    bfrag aO[2][6];
    #pragma unroll
    for (int rt = 0; rt < 2; rt++)
        #pragma unroll
        for (int kb = 0; kb < 6; kb++)
            aO[rt][kb] = *(const bfrag*)&Og[(row0 + r0 + rt * 16 + l15) * 192 + kb * 32 + quad * 8];

    // token scatter addresses (reverse shift)
    size_t tokb[2][4];
    #pragma unroll
    for (int rt = 0; rt < 2; rt++)
        #pragma unroll
        for (int reg = 0; reg < 4; reg++) {
            int n = r0 + rt * 16 + quad * 4 + reg;
            int w2 = (int)(blockIdx.x * 2) + (n >> 6);
            int nl = n & 63;
            int b = w2 >> 8, wi = w2 & 255;
            int wh = wi >> 4, wwi = wi & 15;
            int sr = wh * 8 + (nl >> 3), sc = wwi * 8 + (nl & 7);
            int h2 = (sr + 4) & 127, w2c = (sc + 4) & 127;
            tokb[rt][reg] = ((size_t)(b * 16384 + h2 * 128 + w2c)) * 192;
        }

    __syncthreads();

    ffrag acc[2][12];
    #pragma unroll
    for (int rt = 0; rt < 2; rt++)
        #pragma unroll
        for (int ct = 0; ct < 12; ct++)
            acc[rt][ct] = (ffrag){0.f, 0.f, 0.f, 0.f};

    #pragma unroll
    for (int ct = 0; ct < 12; ct++) {
        bfrag bw[6];
        #pragma unroll
        for (int kb = 0; kb < 6; kb++)
            bw[kb] = *(const bfrag*)&sWp[(ct * 16 + l15) * 200 + kb * 32 + quad * 8];
        #pragma unroll
        for (int rt = 0; rt < 2; rt++)
            #pragma unroll
            for (int kb = 0; kb < 6; kb++)
                acc[rt][ct] = MFMA(aO[rt][kb], bw[kb], acc[rt][ct]);
    }

    #pragma unroll
    for (int rt = 0; rt < 2; rt++)
        #pragma unroll
        for (int ct = 0; ct < 12; ct++) {
            int col = ct * 16 + l15;
            float pb = proj_b[col];
            #pragma unroll
            for (int reg = 0; reg < 4; reg++) {
                size_t gi = tokb[rt][reg] + col;
                xres[gi] = acc[rt][ct][reg] + pb + x[gi];
            }
        }
}

// ---------------------------------------------------------------------------
// k_mlp: 128 rows/block, 4 waves x 32 rows (rt=2). w1+w2 chunks staged per kc.
// LDS 71680 -> 2 blocks/CU.
// ---------------------------------------------------------------------------
__global__ __launch_bounds__(256, 2) void k_mlp(
    const float* __restrict__ xres, const float* __restrict__ g,
    const float* __restrict__ bb, const float* __restrict__ b1,
    const float* __restrict__ b2, const char* __restrict__ ws,
    float* __restrict__ out)
{
    __shared__ __align__(16) unsigned char smem[71680];
    bf16* U   = (bf16*)(smem);             // xn [128][200]; then w1 chunk [64][200]
    bf16* W2s = (bf16*)(smem + 25600);     // w2 chunk [192][72] (27648 B)
    bf16* hS  = (bf16*)(smem + 53248);     // [4][32][72]

    const bf16* w1T = (const bf16*)(ws + WS_W1T);
    const bf16* w2T = (const bf16*)(ws + WS_W2T);

    const int t    = threadIdx.x;
    const int lane = t & 63, quad = lane >> 4, l15 = lane & 15;
    const int wave = t >> 6, r0 = wave * 32;
    const size_t row0 = (size_t)blockIdx.x * 128;

    // ---- wave-local LayerNorm -> xn (bf16, U) ----
    #pragma unroll
    for (int p = 0; p < 2; p++) {
        int row = r0 + p * 16 + l15;
        const float4* src = (const float4*)(xres + (row0 + row) * 192 + quad * 48);
        float v[48];
        float s = 0.f, sq = 0.f;
        #pragma unroll
        for (int u = 0; u < 12; u++) {
            float4 f = src[u];
            v[u*4] = f.x; v[u*4+1] = f.y; v[u*4+2] = f.z; v[u*4+3] = f.w;
            s  += f.x + f.y + f.z + f.w;
            sq += f.x*f.x + f.y*f.y + f.z*f.z + f.w*f.w;
        }
        s  += __shfl_xor(s, 16);  s  += __shfl_xor(s, 32);
        sq += __shfl_xor(sq, 16); sq += __shfl_xor(sq, 32);
        float mean = s * (1.f / 192.f);
        float var  = sq * (1.f / 192.f) - mean * mean;
        float rstd = rsqrtf(var + 1e-5f);
        __hip_bfloat162* dst = (__hip_bfloat162*)&U[row * 200 + quad * 48];
        #pragma unroll
        for (int u = 0; u < 24; u++) {
            int c = quad * 48 + u * 2;
            float a0 = (v[u*2]   - mean) * rstd * g[c]     + bb[c];
            float a1 = (v[u*2+1] - mean) * rstd * g[c + 1] + bb[c + 1];
            dst[u] = __float22bfloat162_rn({a0, a1});
        }
    }

    // A-frags of xn (own rows; within-wave RAW)
    bfrag aX[2][6];
    #pragma unroll
    for (int rt = 0; rt < 2; rt++)
        #pragma unroll
        for (int kb = 0; kb < 6; kb++)
            aX[rt][kb] = *(const bfrag*)&U[(r0 + rt*16 + l15) * 200 + kb*32 + quad*8];

    __syncthreads();   // everyone done with xn region

    bf16* hs_w = hS + wave * 32 * 72;

    ffrag oacc[2][12];
    #pragma unroll
    for (int rt = 0; rt < 2; rt++)
        #pragma unroll
        for (int ct = 0; ct < 12; ct++)
            oacc[rt][ct] = (ffrag){0.f, 0.f, 0.f, 0.f};

    for (int kc = 0; kc < 12; kc++) {
        __syncthreads();                                   // WAR vs previous compute
        stage_lds(w1T + (size_t)kc * 64 * 200, U, 25600, t);
        stage_lds(w2T + (size_t)kc * 13824, W2s, 27648, t);
        __syncthreads();                                   // staging complete

        // MLP1 (64 hidden cols) + GELU -> hS (own rows)
        #pragma unroll
        for (int ct = 0; ct < 4; ct++) {
            bfrag bw[6];
            #pragma unroll
            for (int kb = 0; kb < 6; kb++)
                bw[kb] = *(const bfrag*)&U[(ct*16 + l15) * 200 + kb*32 + quad*8];
            float bias = b1[kc * 64 + ct * 16 + l15];
            #pragma unroll
            for (int rt = 0; rt < 2; rt++) {
                ffrag a = {0.f, 0.f, 0.f, 0.f};
                #pragma unroll
                for (int kb = 0; kb < 6; kb++) a = MFMA(aX[rt][kb], bw[kb], a);
                #pragma unroll
                for (int reg = 0; reg < 4; reg++)
                    hs_w[(rt*16 + quad*4 + reg) * 72 + ct*16 + l15] =
                        f2b(gelu_t(a[reg] + bias));
            }
        }
        // MLP2 over this 64-k chunk
        bfrag aH[2][2];
        #pragma unroll
        for (int rt = 0; rt < 2; rt++)
            #pragma unroll
            for (int k0 = 0; k0 < 2; k0++)
                aH[rt][k0] = *(const bfrag*)&hs_w[(rt*16 + l15) * 72 + k0*32 + quad*8];
        #pragma unroll
        for (int ct = 0; ct < 12; ct++) {
            bfrag bw2[2];
            #pragma unroll
            for (int k0 = 0; k0 < 2; k0++)
                bw2[k0] = *(const bfrag*)&W2s[(ct*16 + l15) * 72 + k0*32 + quad*8];
            #pragma unroll
            for (int rt = 0; rt < 2; rt++)
                #pragma unroll
                for (int k0 = 0; k0 < 2; k0++)
                    oacc[rt][ct] = MFMA(aH[rt][k0], bw2[k0], oacc[rt][ct]);
        }
    }

    // ---- epilogue: out = xres + mlp + b2 ----
    #pragma unroll
    for (int rt = 0; rt < 2; rt++)
        #pragma unroll
        for (int ct = 0; ct < 12; ct++) {
            int col = ct * 16 + l15;
            float b2v = b2[col];
            #pragma unroll
            for (int reg = 0; reg < 4; reg++) {
                size_t gi = (row0 + r0 + rt*16 + quad*4 + reg) * 192 + col;
                out[gi] = xres[gi] + oacc[rt][ct][reg] + b2v;
            }
        }
}

// ---------------------------------------------------------------------------
extern "C" void kernel_launch(void* const* d_in, const int* in_sizes, int n_in,
                              void* d_out, int out_size, void* d_ws, size_t ws_size,
                              hipStream_t stream)
{
    (void)in_sizes; (void)n_in; (void)out_size; (void)ws_size;

    const float* x      = (const float*)d_in[0];
    const float* qkv_w  = (const float*)d_in[1];
    const float* qkv_b  = (const float*)d_in[2];
    const float* proj_w = (const float*)d_in[3];
    const float* proj_b = (const float*)d_in[4];
    const float* rpb    = (const float*)d_in[5];
    const float* n2g    = (const float*)d_in[6];
    const float* n2b    = (const float*)d_in[7];
    const float* w1     = (const float*)d_in[8];
    const float* b1     = (const float*)d_in[9];
    const float* w2     = (const float*)d_in[10];
    const float* b2     = (const float*)d_in[11];

    char*  ws   = (char*)d_ws;
    float* xres = (float*)(ws + WS_XRES);
    bf16*  Og   = (bf16*)(ws + WS_OG);
    float* out  = (float*)d_out;

    hipLaunchKernelGGL(k_prep, dim3(2285), dim3(256), 0, stream,
                       qkv_w, qkv_b, proj_w, w1, w2, rpb, ws);
    hipLaunchKernelGGL(k_attn, dim3(2048), dim3(256), 0, stream,
                       x, ws, Og);
    hipLaunchKernelGGL(k_proj, dim3(1024), dim3(256), 0, stream,
                       x, proj_b, ws, xres);
    hipLaunchKernelGGL(k_mlp,  dim3(1024), dim3(256), 0, stream,
                       xres, n2g, n2b, b1, b2, ws, out);
}